// Round 1
// baseline (33449.066 us; speedup 1.0000x reference)
//
#include <hip/hip_runtime.h>
#include <hip/hip_cooperative_groups.h>

namespace cg = cooperative_groups;

typedef __attribute__((ext_vector_type(8))) short short8;
typedef __attribute__((ext_vector_type(4))) float f32x4;

#define NB 64
#define NS 512
#define NF 128
#define NH 512
#define NG 2048  // 4*H

__device__ __forceinline__ unsigned short f2bf(float f) {
    unsigned int u = __builtin_bit_cast(unsigned int, f);
    u = (u + 0x7fffu + ((u >> 16) & 1u)) >> 16;
    return (unsigned short)u;
}
__device__ __forceinline__ float sigm(float x) { return 1.0f / (1.0f + __expf(-x)); }
__device__ __forceinline__ float tanh_(float x) {
    float e = __expf(2.0f * fabsf(x));
    float r = 1.0f - 2.0f / (e + 1.0f);
    return x < 0.0f ? -r : r;
}

__global__ void cvt_bf16(const float* __restrict__ in, unsigned short* __restrict__ out, int n) {
    int i = blockIdx.x * blockDim.x + threadIdx.x;
    int stride = gridDim.x * blockDim.x;
    for (; i < n; i += stride) out[i] = f2bf(in[i]);
}

// out[n][k] = bf16(in[k][n])   in: [K][N] f32 row-major
__global__ void tr_cvt(const float* __restrict__ in, unsigned short* __restrict__ out, int K, int N) {
    int i = blockIdx.x * blockDim.x + threadIdx.x;
    if (i >= K * N) return;
    int n = i / K, k = i - n * K;
    out[i] = f2bf(in[k * N + n]);
}

// Persistent cooperative 2-layer LSTM.
// grid = 256 blocks = 4 batch-groups (16 rows) x 64 col-tiles (8 h-cols).
// block = 1 wave (64 threads). LDS: weight slice [32 gate-cols][512+Kx] bf16, XOR-swizzled.
// MFMA tile0 = gates {i(hc0..7), f(hc0..7)}, tile1 = {g, o}; epilogue shfl_xor(8)
// gives every lane (i,f,g,o) for its (row, hcol); c-state in registers (fp32).
__global__ void __launch_bounds__(64, 1) lstm_coop(
    const unsigned short* __restrict__ xbf,
    unsigned short* __restrict__ h0,
    unsigned short* __restrict__ h1,
    const unsigned short* __restrict__ whT0,
    const unsigned short* __restrict__ wxT0,
    const unsigned short* __restrict__ whT1,
    const unsigned short* __restrict__ wxT1,
    const float* __restrict__ b0,
    const float* __restrict__ b1,
    float* __restrict__ hlast)
{
    cg::grid_group grid = cg::this_grid();
    __shared__ unsigned short wlds[32 * 1024];  // 64 KB, rows of 2048 B

    const int lane = threadIdx.x;
    const int c16 = lane & 15;
    const int kg  = lane >> 4;
    const int blk = blockIdx.x;
    const int bg  = blk >> 6;   // 0..3
    const int ct  = blk & 63;   // 0..63

    for (int layer = 0; layer < 2; ++layer) {
        const unsigned short* whT  = layer ? whT1 : whT0;   // [2048][512]
        const unsigned short* wxT  = layer ? wxT1 : wxT0;   // [2048][Kx]
        const float* bias          = layer ? b1 : b0;
        const unsigned short* xsrc = layer ? h0 : xbf;      // [B][S][Kx]
        unsigned short* hseq       = layer ? h1 : h0;       // [B][S][H]
        const int Kx  = layer ? NH : NF;
        const int kxs = Kx >> 5;              // k-steps for x part
        const int cpr = (NH + Kx) >> 3;       // 16B chunks per LDS row

        __syncthreads();
        // load weight slice: local row n -> gate q=n>>3, hcol ct*8+(n&7)
        for (int idx = lane; idx < 32 * cpr; idx += 64) {
            int n = idx / cpr, cc = idx - n * cpr;
            int G = (n >> 3) * NH + ct * 8 + (n & 7);
            uint4 v;
            if (cc < 64) v = *(const uint4*)(whT + (size_t)G * NH + cc * 8);
            else         v = *(const uint4*)(wxT + (size_t)G * Kx + (size_t)(cc - 64) * 8);
            *(uint4*)((char*)wlds + n * 2048 + ((cc * 16) ^ ((n & 7) << 4))) = v;
        }
        __syncthreads();

        const int hc8 = c16 & 7;
        const float bi  = bias[0 * NH + ct * 8 + hc8];
        const float bf_ = bias[1 * NH + ct * 8 + hc8];
        const float bg_ = bias[2 * NH + ct * 8 + hc8];
        const float bo  = bias[3 * NH + ct * 8 + hc8];

        const int arow = bg * 16 + c16;           // A-frag row this lane loads
        const size_t aseq = (size_t)arow * NS;
        float cst[4] = {0.f, 0.f, 0.f, 0.f};

        const char* ldsA = (const char*)wlds + (size_t)c16 * 2048;         // tile0 row
        const char* ldsB = (const char*)wlds + (size_t)(16 + c16) * 2048;  // tile1 row
        const int swzA = (c16 & 7) << 4;
        const int swzB = ((16 + c16) & 7) << 4;

        for (int t = 0; t < NS; ++t) {
            f32x4 acc0 = {0.f, 0.f, 0.f, 0.f};
            f32x4 acc1 = {0.f, 0.f, 0.f, 0.f};
            if (t > 0) {
                const unsigned short* hp = hseq + (aseq + (t - 1)) * NH + kg * 8;
                #pragma unroll
                for (int ks = 0; ks < 16; ++ks) {
                    short8 a  = *(const short8*)(hp + ks * 32);
                    short8 w0 = *(const short8*)(ldsA + ((ks * 64 + kg * 16) ^ swzA));
                    short8 w1 = *(const short8*)(ldsB + ((ks * 64 + kg * 16) ^ swzB));
                    acc0 = __builtin_amdgcn_mfma_f32_16x16x32_bf16(a, w0, acc0, 0, 0, 0);
                    acc1 = __builtin_amdgcn_mfma_f32_16x16x32_bf16(a, w1, acc1, 0, 0, 0);
                }
            }
            {
                const unsigned short* xp = xsrc + (aseq + t) * Kx + kg * 8;
                #pragma unroll 4
                for (int ks = 0; ks < kxs; ++ks) {
                    short8 a = *(const short8*)(xp + ks * 32);
                    int boff = 1024 + ks * 64 + kg * 16;
                    short8 w0 = *(const short8*)(ldsA + (boff ^ swzA));
                    short8 w1 = *(const short8*)(ldsB + (boff ^ swzB));
                    acc0 = __builtin_amdgcn_mfma_f32_16x16x32_bf16(a, w0, acc0, 0, 0, 0);
                    acc1 = __builtin_amdgcn_mfma_f32_16x16x32_bf16(a, w1, acc1, 0, 0, 0);
                }
            }
            // epilogue: lane l and l^8 hold {i,f} / {g,o} swapped for same hcol
            f32x4 s0, s1;
            #pragma unroll
            for (int i = 0; i < 4; ++i) {
                s0[i] = __shfl_xor(acc0[i], 8, 64);
                s1[i] = __shfl_xor(acc1[i], 8, 64);
            }
            const bool lower = (c16 < 8);
            unsigned short* hw = hseq + ((size_t)(bg * 16 + kg * 4) * NS + t) * NH + ct * 8 + hc8;
            #pragma unroll
            for (int i = 0; i < 4; ++i) {
                float gi = (lower ? acc0[i] : s0[i]) + bi;
                float gf = (lower ? s0[i] : acc0[i]) + bf_;
                float gg = (lower ? acc1[i] : s1[i]) + bg_;
                float go = (lower ? s1[i] : acc1[i]) + bo;
                float c_ = sigm(gf) * cst[i] + sigm(gi) * tanh_(gg);
                cst[i] = c_;
                float hv = sigm(go) * tanh_(c_);
                hw[(size_t)i * NS * NH] = f2bf(hv);
                if (layer == 1 && t == NS - 1)
                    hlast[(bg * 16 + kg * 4 + i) * NH + ct * 8 + hc8] = hv;
            }
            grid.sync();
        }
    }
}

// one block per batch row; mode 1 = relu, 2 = sigmoid
__global__ void dense(const float* __restrict__ in, const float* __restrict__ W,
                      const float* __restrict__ bias, float* __restrict__ out,
                      int K, int N, int mode) {
    int b = blockIdx.x;
    int j = threadIdx.x;
    extern __shared__ float srow[];
    for (int k = j; k < K; k += blockDim.x) srow[k] = in[b * K + k];
    __syncthreads();
    if (j < N) {
        float acc = bias[j];
        for (int k = 0; k < K; ++k) acc += srow[k] * W[k * N + j];
        if (mode == 1) acc = fmaxf(acc, 0.0f);
        else           acc = 1.0f / (1.0f + __expf(-acc));
        out[b * N + j] = acc;
    }
}

extern "C" void kernel_launch(void* const* d_in, const int* in_sizes, int n_in,
                              void* d_out, int out_size, void* d_ws, size_t ws_size,
                              hipStream_t stream) {
    const float* x    = (const float*)d_in[0];
    const float* Wx0  = (const float*)d_in[1];
    const float* Wh0  = (const float*)d_in[2];
    const float* b0   = (const float*)d_in[3];
    const float* Wx1  = (const float*)d_in[4];
    const float* Wh1  = (const float*)d_in[5];
    const float* b1   = (const float*)d_in[6];
    const float* Wd0  = (const float*)d_in[7];
    const float* bd0  = (const float*)d_in[8];
    const float* Wd1  = (const float*)d_in[9];
    const float* bd1  = (const float*)d_in[10];
    const float* Wout = (const float*)d_in[11];
    const float* bout = (const float*)d_in[12];

    char* ws = (char*)d_ws;
    size_t off = 0;
    auto alloc = [&](size_t bytes) { void* p = ws + off; off += (bytes + 255) & ~255ull; return p; };
    unsigned short* xbf  = (unsigned short*)alloc((size_t)NB * NS * NF * 2);
    unsigned short* h0   = (unsigned short*)alloc((size_t)NB * NS * NH * 2);
    unsigned short* h1   = (unsigned short*)alloc((size_t)NB * NS * NH * 2);
    unsigned short* whT0 = (unsigned short*)alloc((size_t)NG * NH * 2);
    unsigned short* wxT0 = (unsigned short*)alloc((size_t)NG * NF * 2);
    unsigned short* whT1 = (unsigned short*)alloc((size_t)NG * NH * 2);
    unsigned short* wxT1 = (unsigned short*)alloc((size_t)NG * NH * 2);
    float* hlast = (float*)alloc((size_t)NB * NH * 4);
    float* dt0   = (float*)alloc((size_t)NB * 512 * 4);
    float* dt1   = (float*)alloc((size_t)NB * 256 * 4);

    cvt_bf16<<<2048, 256, 0, stream>>>(x, xbf, NB * NS * NF);
    tr_cvt<<<(NG * NF + 255) / 256, 256, 0, stream>>>(Wx0, wxT0, NF, NG);
    tr_cvt<<<(NG * NH + 255) / 256, 256, 0, stream>>>(Wh0, whT0, NH, NG);
    tr_cvt<<<(NG * NH + 255) / 256, 256, 0, stream>>>(Wx1, wxT1, NH, NG);
    tr_cvt<<<(NG * NH + 255) / 256, 256, 0, stream>>>(Wh1, whT1, NH, NG);

    void* args[] = { (void*)&xbf, (void*)&h0, (void*)&h1,
                     (void*)&whT0, (void*)&wxT0, (void*)&whT1, (void*)&wxT1,
                     (void*)&b0, (void*)&b1, (void*)&hlast };
    hipLaunchCooperativeKernel((void*)lstm_coop, dim3(256), dim3(64), args, 0, stream);

    dense<<<NB, 512, 512 * 4, stream>>>(hlast, Wd0, bd0, dt0, 512, 512, 1);
    dense<<<NB, 256, 512 * 4, stream>>>(dt0, Wd1, bd1, dt1, 512, 256, 1);
    dense<<<NB, 128, 256 * 4, stream>>>(dt1, Wout, bout, (float*)d_out, 256, 96, 2);
}

// Round 2
// 10032.162 us; speedup vs baseline: 3.3342x; 3.3342x over previous
//
#include <hip/hip_runtime.h>

typedef __attribute__((ext_vector_type(8))) short short8;
typedef __attribute__((ext_vector_type(4))) float f32x4;

#define NB 64
#define NS 512
#define NF 128
#define NH 512
#define NG 2048  // 4*H
#define NBLK 256

__device__ __forceinline__ unsigned short f2bf(float f) {
    unsigned int u = __builtin_bit_cast(unsigned int, f);
    u = (u + 0x7fffu + ((u >> 16) & 1u)) >> 16;
    return (unsigned short)u;
}
__device__ __forceinline__ float sigm(float x) { return 1.0f / (1.0f + __expf(-x)); }
__device__ __forceinline__ float tanh_(float x) {
    float e = __expf(2.0f * fabsf(x));
    float r = 1.0f - 2.0f / (e + 1.0f);
    return x < 0.0f ? -r : r;
}

// agent-scope (L2-bypassing, L3-coherent) 16B load as 2x8B
__device__ __forceinline__ short8 cohld16(const unsigned short* p) {
    unsigned long long* q = (unsigned long long*)p;
    union { unsigned long long u[2]; short8 s; } v;
    v.u[0] = __hip_atomic_load(q,     __ATOMIC_RELAXED, __HIP_MEMORY_SCOPE_AGENT);
    v.u[1] = __hip_atomic_load(q + 1, __ATOMIC_RELAXED, __HIP_MEMORY_SCOPE_AGENT);
    return v.s;
}
__device__ __forceinline__ void cohst2(unsigned short* p, unsigned short v) {
    __hip_atomic_store(p, v, __ATOMIC_RELAXED, __HIP_MEMORY_SCOPE_AGENT);
}

// global flag barrier: no cache maintenance (h traffic is L2-bypassing).
__device__ __forceinline__ void gbar(unsigned* cnt, unsigned tgt) {
    asm volatile("" ::: "memory");
    asm volatile("s_waitcnt vmcnt(0)" ::: "memory");   // h stores at coherence point
    if (threadIdx.x == 0)
        __hip_atomic_fetch_add(cnt, 1u, __ATOMIC_RELAXED, __HIP_MEMORY_SCOPE_AGENT);
    while (__hip_atomic_load(cnt, __ATOMIC_RELAXED, __HIP_MEMORY_SCOPE_AGENT) < tgt)
        __builtin_amdgcn_s_sleep(2);
    __builtin_amdgcn_sched_barrier(0);
    asm volatile("" ::: "memory");
}

__global__ void cvt_bf16(const float* __restrict__ in, unsigned short* __restrict__ out, int n) {
    int i = blockIdx.x * blockDim.x + threadIdx.x;
    int stride = gridDim.x * blockDim.x;
    for (; i < n; i += stride) out[i] = f2bf(in[i]);
}

// out[n][k] = bf16(in[k][n])   in: [K][N] f32 row-major
__global__ void tr_cvt(const float* __restrict__ in, unsigned short* __restrict__ out, int K, int N) {
    int i = blockIdx.x * blockDim.x + threadIdx.x;
    if (i >= K * N) return;
    int n = i / K, k = i - n * K;
    out[i] = f2bf(in[k * N + n]);
}

template<int LAYER>
__device__ __forceinline__ void run_layer(
    unsigned short* wlds,
    const unsigned short* __restrict__ xsrc,   // [B][S][Kx]
    unsigned short* __restrict__ hseq,         // [B][S][H]
    const unsigned short* __restrict__ whT,    // [2048][512]
    const unsigned short* __restrict__ wxT,    // [2048][Kx]
    const float* __restrict__ bias,
    float* __restrict__ hlast,
    unsigned* barcnt, unsigned& bars,
    int lane, int bg, int ct)
{
    const int c16 = lane & 15;
    const int kg  = lane >> 4;
    const int Kx  = LAYER ? NH : NF;
    const int kxs = Kx >> 5;
    const int cpr = (NH + Kx) >> 3;

    __syncthreads();
    // load weight slice: local row n -> gate q=n>>3, hcol ct*8+(n&7)
    for (int idx = lane; idx < 32 * cpr; idx += 64) {
        int n = idx / cpr, cc = idx - n * cpr;
        int G = (n >> 3) * NH + ct * 8 + (n & 7);
        uint4 v;
        if (cc < 64) v = *(const uint4*)(whT + (size_t)G * NH + cc * 8);
        else         v = *(const uint4*)(wxT + (size_t)G * Kx + (size_t)(cc - 64) * 8);
        *(uint4*)((char*)wlds + n * 2048 + ((cc * 16) ^ ((n & 7) << 4))) = v;
    }
    __syncthreads();

    const int hc8 = c16 & 7;
    const float bi  = bias[0 * NH + ct * 8 + hc8];
    const float bf_ = bias[1 * NH + ct * 8 + hc8];
    const float bg_ = bias[2 * NH + ct * 8 + hc8];
    const float bo  = bias[3 * NH + ct * 8 + hc8];

    const int arow = bg * 16 + c16;
    const size_t aseq = (size_t)arow * NS;
    float cst[4] = {0.f, 0.f, 0.f, 0.f};

    const char* ldsA = (const char*)wlds + (size_t)c16 * 2048;
    const char* ldsB = (const char*)wlds + (size_t)(16 + c16) * 2048;
    const int swzA = (c16 & 7) << 4;
    const int swzB = ((16 + c16) & 7) << 4;

    for (int t = 0; t < NS; ++t) {
        f32x4 acc0 = {0.f, 0.f, 0.f, 0.f};
        f32x4 acc1 = {0.f, 0.f, 0.f, 0.f};
        if (t > 0) {
            const unsigned short* hp = hseq + (aseq + (t - 1)) * NH + kg * 8;
            #pragma unroll
            for (int ks = 0; ks < 16; ++ks) {
                short8 a  = cohld16(hp + ks * 32);
                short8 w0 = *(const short8*)(ldsA + ((ks * 64 + kg * 16) ^ swzA));
                short8 w1 = *(const short8*)(ldsB + ((ks * 64 + kg * 16) ^ swzB));
                acc0 = __builtin_amdgcn_mfma_f32_16x16x32_bf16(a, w0, acc0, 0, 0, 0);
                acc1 = __builtin_amdgcn_mfma_f32_16x16x32_bf16(a, w1, acc1, 0, 0, 0);
            }
        }
        {
            const unsigned short* xp = xsrc + (aseq + t) * Kx + kg * 8;
            #pragma unroll
            for (int ks = 0; ks < kxs; ++ks) {
                short8 a = LAYER ? cohld16(xp + ks * 32)
                                 : *(const short8*)(xp + ks * 32);
                int boff = 1024 + ks * 64 + kg * 16;
                short8 w0 = *(const short8*)(ldsA + (boff ^ swzA));
                short8 w1 = *(const short8*)(ldsB + (boff ^ swzB));
                acc0 = __builtin_amdgcn_mfma_f32_16x16x32_bf16(a, w0, acc0, 0, 0, 0);
                acc1 = __builtin_amdgcn_mfma_f32_16x16x32_bf16(a, w1, acc1, 0, 0, 0);
            }
        }
        // epilogue: lane l and l^8 hold {i,f} / {g,o} swapped for same hcol
        f32x4 s0, s1;
        #pragma unroll
        for (int i = 0; i < 4; ++i) {
            s0[i] = __shfl_xor(acc0[i], 8, 64);
            s1[i] = __shfl_xor(acc1[i], 8, 64);
        }
        const bool lower = (c16 < 8);
        unsigned short* hw = hseq + ((size_t)(bg * 16 + kg * 4) * NS + t) * NH + ct * 8 + hc8;
        #pragma unroll
        for (int i = 0; i < 4; ++i) {
            float gi = (lower ? acc0[i] : s0[i]) + bi;
            float gf = (lower ? s0[i] : acc0[i]) + bf_;
            float gg = (lower ? acc1[i] : s1[i]) + bg_;
            float go = (lower ? s1[i] : acc1[i]) + bo;
            float c_ = sigm(gf) * cst[i] + sigm(gi) * tanh_(gg);
            cst[i] = c_;
            float hv = sigm(go) * tanh_(c_);
            if (lower) {
                cohst2(hw + (size_t)i * NS * NH, f2bf(hv));
                if (LAYER == 1 && t == NS - 1)
                    hlast[(bg * 16 + kg * 4 + i) * NH + ct * 8 + hc8] = hv;
            }
        }
        gbar(barcnt, (++bars) * NBLK);
    }
}

// Persistent 2-layer LSTM; custom flag barrier instead of cg::grid.sync()
// (grid.sync's agent release/acquire = full L2 wb+inv per step on 8-XCD chip).
__global__ void __launch_bounds__(64, 1) lstm_coop(
    const unsigned short* __restrict__ xbf,
    unsigned short* __restrict__ h0,
    unsigned short* __restrict__ h1,
    const unsigned short* __restrict__ whT0,
    const unsigned short* __restrict__ wxT0,
    const unsigned short* __restrict__ whT1,
    const unsigned short* __restrict__ wxT1,
    const float* __restrict__ b0,
    const float* __restrict__ b1,
    float* __restrict__ hlast,
    unsigned* __restrict__ barcnt)
{
    __shared__ unsigned short wlds[32 * 1024];  // 64 KB

    const int lane = threadIdx.x;
    const int bg   = blockIdx.x >> 6;   // 0..3
    const int ct   = blockIdx.x & 63;   // 0..63
    unsigned bars = 0;

    run_layer<0>(wlds, xbf, h0, whT0, wxT0, b0, hlast, barcnt, bars, lane, bg, ct);
    run_layer<1>(wlds, h0,  h1, whT1, wxT1, b1, hlast, barcnt, bars, lane, bg, ct);
}

// one block per batch row; mode 1 = relu, 2 = sigmoid
__global__ void dense(const float* __restrict__ in, const float* __restrict__ W,
                      const float* __restrict__ bias, float* __restrict__ out,
                      int K, int N, int mode) {
    int b = blockIdx.x;
    int j = threadIdx.x;
    extern __shared__ float srow[];
    for (int k = j; k < K; k += blockDim.x) srow[k] = in[b * K + k];
    __syncthreads();
    if (j < N) {
        float acc = bias[j];
        for (int k = 0; k < K; ++k) acc += srow[k] * W[k * N + j];
        if (mode == 1) acc = fmaxf(acc, 0.0f);
        else           acc = 1.0f / (1.0f + __expf(-acc));
        out[b * N + j] = acc;
    }
}

extern "C" void kernel_launch(void* const* d_in, const int* in_sizes, int n_in,
                              void* d_out, int out_size, void* d_ws, size_t ws_size,
                              hipStream_t stream) {
    const float* x    = (const float*)d_in[0];
    const float* Wx0  = (const float*)d_in[1];
    const float* Wh0  = (const float*)d_in[2];
    const float* b0   = (const float*)d_in[3];
    const float* Wx1  = (const float*)d_in[4];
    const float* Wh1  = (const float*)d_in[5];
    const float* b1   = (const float*)d_in[6];
    const float* Wd0  = (const float*)d_in[7];
    const float* bd0  = (const float*)d_in[8];
    const float* Wd1  = (const float*)d_in[9];
    const float* bd1  = (const float*)d_in[10];
    const float* Wout = (const float*)d_in[11];
    const float* bout = (const float*)d_in[12];

    char* ws = (char*)d_ws;
    size_t off = 0;
    auto alloc = [&](size_t bytes) { void* p = ws + off; off += (bytes + 255) & ~255ull; return p; };
    unsigned* barcnt = (unsigned*)alloc(256);
    unsigned short* xbf  = (unsigned short*)alloc((size_t)NB * NS * NF * 2);
    unsigned short* h0   = (unsigned short*)alloc((size_t)NB * NS * NH * 2);
    unsigned short* h1   = (unsigned short*)alloc((size_t)NB * NS * NH * 2);
    unsigned short* whT0 = (unsigned short*)alloc((size_t)NG * NH * 2);
    unsigned short* wxT0 = (unsigned short*)alloc((size_t)NG * NF * 2);
    unsigned short* whT1 = (unsigned short*)alloc((size_t)NG * NH * 2);
    unsigned short* wxT1 = (unsigned short*)alloc((size_t)NG * NH * 2);
    float* hlast = (float*)alloc((size_t)NB * NH * 4);
    float* dt0   = (float*)alloc((size_t)NB * 512 * 4);
    float* dt1   = (float*)alloc((size_t)NB * 256 * 4);

    hipMemsetAsync(barcnt, 0, 256, stream);
    cvt_bf16<<<2048, 256, 0, stream>>>(x, xbf, NB * NS * NF);
    tr_cvt<<<(NG * NF + 255) / 256, 256, 0, stream>>>(Wx0, wxT0, NF, NG);
    tr_cvt<<<(NG * NH + 255) / 256, 256, 0, stream>>>(Wh0, whT0, NH, NG);
    tr_cvt<<<(NG * NH + 255) / 256, 256, 0, stream>>>(Wx1, wxT1, NH, NG);
    tr_cvt<<<(NG * NH + 255) / 256, 256, 0, stream>>>(Wh1, whT1, NH, NG);

    void* args[] = { (void*)&xbf, (void*)&h0, (void*)&h1,
                     (void*)&whT0, (void*)&wxT0, (void*)&whT1, (void*)&wxT1,
                     (void*)&b0, (void*)&b1, (void*)&hlast, (void*)&barcnt };
    hipLaunchCooperativeKernel((void*)lstm_coop, dim3(NBLK), dim3(64), args, 0, stream);

    dense<<<NB, 512, 512 * 4, stream>>>(hlast, Wd0, bd0, dt0, 512, 512, 1);
    dense<<<NB, 256, 512 * 4, stream>>>(dt0, Wd1, bd1, dt1, 512, 256, 1);
    dense<<<NB, 128, 256 * 4, stream>>>(dt1, Wout, bout, (float*)d_out, 256, 96, 2);
}

// Round 3
// 6809.573 us; speedup vs baseline: 4.9121x; 1.4732x over previous
//
#include <hip/hip_runtime.h>

typedef __attribute__((ext_vector_type(8))) short short8;
typedef __attribute__((ext_vector_type(4))) float f32x4;

#define NB 64
#define NS 512
#define NF 128
#define NH 512
#define NG 2048  // 4*H
#define NBLK 256

__device__ __forceinline__ unsigned short f2bf(float f) {
    unsigned int u = __builtin_bit_cast(unsigned int, f);
    u = (u + 0x7fffu + ((u >> 16) & 1u)) >> 16;
    return (unsigned short)u;
}
__device__ __forceinline__ float sigm(float x) { return 1.0f / (1.0f + __expf(-x)); }
__device__ __forceinline__ float tanh_(float x) {
    float e = __expf(2.0f * fabsf(x));
    float r = 1.0f - 2.0f / (e + 1.0f);
    return x < 0.0f ? -r : r;
}

// agent-scope (L2-bypassing, L3-coherent) 16B load as 2x8B
__device__ __forceinline__ short8 cohld16(const unsigned short* p) {
    unsigned long long* q = (unsigned long long*)p;
    union { unsigned long long u[2]; short8 s; } v;
    v.u[0] = __hip_atomic_load(q,     __ATOMIC_RELAXED, __HIP_MEMORY_SCOPE_AGENT);
    v.u[1] = __hip_atomic_load(q + 1, __ATOMIC_RELAXED, __HIP_MEMORY_SCOPE_AGENT);
    return v.s;
}
__device__ __forceinline__ void cohst2(unsigned short* p, unsigned short v) {
    __hip_atomic_store(p, v, __ATOMIC_RELAXED, __HIP_MEMORY_SCOPE_AGENT);
}

// Distributed flag barrier (per batch-group, 64 participants):
// - signal: wait own h-stores (vmcnt 0), then store my step count to MY flag
//   word (no RMW, no shared-address contention).
// - wait: lane i spins on flags[i] >= tgt; divergent per-lane exit reconverges
//   exactly when all 64 producer blocks have signaled.
__device__ __forceinline__ void flag_signal(unsigned* myflag, unsigned val, int lane) {
    asm volatile("s_waitcnt vmcnt(0)" ::: "memory");
    if (lane == 0)
        __hip_atomic_store(myflag, val, __ATOMIC_RELAXED, __HIP_MEMORY_SCOPE_AGENT);
}
__device__ __forceinline__ void flag_wait(const unsigned* flags, int lane, unsigned tgt) {
    while (__hip_atomic_load(&flags[lane], __ATOMIC_RELAXED, __HIP_MEMORY_SCOPE_AGENT) < tgt)
        __builtin_amdgcn_s_sleep(1);
    __builtin_amdgcn_sched_barrier(0);
    asm volatile("" ::: "memory");
}

__global__ void cvt_bf16(const float* __restrict__ in, unsigned short* __restrict__ out, int n) {
    int i = blockIdx.x * blockDim.x + threadIdx.x;
    int stride = gridDim.x * blockDim.x;
    for (; i < n; i += stride) out[i] = f2bf(in[i]);
}

// out[n][k] = bf16(in[k][n])   in: [K][N] f32 row-major
__global__ void tr_cvt(const float* __restrict__ in, unsigned short* __restrict__ out, int K, int N) {
    int i = blockIdx.x * blockDim.x + threadIdx.x;
    if (i >= K * N) return;
    int n = i / K, k = i - n * K;
    out[i] = f2bf(in[k * N + n]);
}

template<int LAYER>
__device__ __forceinline__ void run_layer(
    unsigned short* wlds,
    const unsigned short* __restrict__ xsrc,   // [B][S][Kx]
    unsigned short* __restrict__ hseq,         // [B][S][H]
    const unsigned short* __restrict__ whT,    // [2048][512]
    const unsigned short* __restrict__ wxT,    // [2048][Kx]
    const float* __restrict__ bias,
    float* __restrict__ hlast,
    unsigned* __restrict__ flags,              // this bg's 64 flags
    unsigned base,                             // LAYER*NS
    int lane, int bg, int ct)
{
    const int c16 = lane & 15;
    const int kg  = lane >> 4;
    const int Kx  = LAYER ? NH : NF;
    const int kxs = Kx >> 5;
    const int cpr = (NH + Kx) >> 3;

    __syncthreads();
    // load weight slice: local row n -> gate q=n>>3, hcol ct*8+(n&7)
    for (int idx = lane; idx < 32 * cpr; idx += 64) {
        int n = idx / cpr, cc = idx - n * cpr;
        int G = (n >> 3) * NH + ct * 8 + (n & 7);
        uint4 v;
        if (cc < 64) v = *(const uint4*)(whT + (size_t)G * NH + cc * 8);
        else         v = *(const uint4*)(wxT + (size_t)G * Kx + (size_t)(cc - 64) * 8);
        *(uint4*)((char*)wlds + n * 2048 + ((cc * 16) ^ ((n & 7) << 4))) = v;
    }
    __syncthreads();

    const int hc8 = c16 & 7;
    const float bi  = bias[0 * NH + ct * 8 + hc8];
    const float bf_ = bias[1 * NH + ct * 8 + hc8];
    const float bg_ = bias[2 * NH + ct * 8 + hc8];
    const float bo  = bias[3 * NH + ct * 8 + hc8];

    const int arow = bg * 16 + c16;
    const size_t aseq = (size_t)arow * NS;
    float cst[4] = {0.f, 0.f, 0.f, 0.f};

    const char* ldsA = (const char*)wlds + (size_t)c16 * 2048;
    const char* ldsB = (const char*)wlds + (size_t)(16 + c16) * 2048;
    const int swzA = (c16 & 7) << 4;
    const int swzB = ((16 + c16) & 7) << 4;

    // x-part of step t (independent of recurrence) — computed early to
    // overlap with other blocks' h-stores / our barrier slack.
    auto xpart = [&](int t, f32x4& a0, f32x4& a1) {
        const unsigned short* xp = xsrc + (aseq + t) * Kx + kg * 8;
        #pragma unroll
        for (int ks = 0; ks < kxs; ++ks) {
            short8 a = LAYER ? cohld16(xp + ks * 32)
                             : *(const short8*)(xp + ks * 32);
            int boff = 1024 + ks * 64 + kg * 16;
            short8 w0 = *(const short8*)(ldsA + (boff ^ swzA));
            short8 w1 = *(const short8*)(ldsB + (boff ^ swzB));
            a0 = __builtin_amdgcn_mfma_f32_16x16x32_bf16(a, w0, a0, 0, 0, 0);
            a1 = __builtin_amdgcn_mfma_f32_16x16x32_bf16(a, w1, a1, 0, 0, 0);
        }
    };

    f32x4 accx0 = {0.f, 0.f, 0.f, 0.f};
    f32x4 accx1 = {0.f, 0.f, 0.f, 0.f};
    xpart(0, accx0, accx1);

    for (int t = 0; t < NS; ++t) {
        f32x4 acc0 = accx0;
        f32x4 acc1 = accx1;
        if (t > 0) {
            flag_wait(flags, lane, base + t);   // all bg blocks stored h[t-1]
            const unsigned short* hp = hseq + (aseq + (t - 1)) * NH + kg * 8;
            #pragma unroll
            for (int ks = 0; ks < 16; ++ks) {
                short8 a  = cohld16(hp + ks * 32);
                short8 w0 = *(const short8*)(ldsA + ((ks * 64 + kg * 16) ^ swzA));
                short8 w1 = *(const short8*)(ldsB + ((ks * 64 + kg * 16) ^ swzB));
                acc0 = __builtin_amdgcn_mfma_f32_16x16x32_bf16(a, w0, acc0, 0, 0, 0);
                acc1 = __builtin_amdgcn_mfma_f32_16x16x32_bf16(a, w1, acc1, 0, 0, 0);
            }
        }
        // epilogue: lane l and l^8 hold {i,f} / {g,o} swapped for same hcol
        f32x4 s0, s1;
        #pragma unroll
        for (int i = 0; i < 4; ++i) {
            s0[i] = __shfl_xor(acc0[i], 8, 64);
            s1[i] = __shfl_xor(acc1[i], 8, 64);
        }
        const bool lower = (c16 < 8);
        unsigned short* hw = hseq + ((size_t)(bg * 16 + kg * 4) * NS + t) * NH + ct * 8 + hc8;
        #pragma unroll
        for (int i = 0; i < 4; ++i) {
            float gi = (lower ? acc0[i] : s0[i]) + bi;
            float gf = (lower ? s0[i] : acc0[i]) + bf_;
            float gg = (lower ? acc1[i] : s1[i]) + bg_;
            float go = (lower ? s1[i] : acc1[i]) + bo;
            float c_ = sigm(gf) * cst[i] + sigm(gi) * tanh_(gg);
            cst[i] = c_;
            float hv = sigm(go) * tanh_(c_);
            if (lower) {
                cohst2(hw + (size_t)i * NS * NH, f2bf(hv));
                if (LAYER == 1 && t == NS - 1)
                    hlast[(bg * 16 + kg * 4 + i) * NH + ct * 8 + hc8] = hv;
            }
        }
        flag_signal(&flags[ct], base + t + 1, lane);
        accx0 = (f32x4){0.f, 0.f, 0.f, 0.f};
        accx1 = (f32x4){0.f, 0.f, 0.f, 0.f};
        if (t + 1 < NS) xpart(t + 1, accx0, accx1);  // overlap with others' signal/poll
    }
    flag_wait(flags, lane, base + NS);  // layer fully written before next layer reads
}

// Persistent 2-layer LSTM; per-batch-group distributed flag barriers
// (4 independent sync domains of 64 blocks; no contended atomicAdd line).
__global__ void __launch_bounds__(64, 1) lstm_coop(
    const unsigned short* __restrict__ xbf,
    unsigned short* __restrict__ h0,
    unsigned short* __restrict__ h1,
    const unsigned short* __restrict__ whT0,
    const unsigned short* __restrict__ wxT0,
    const unsigned short* __restrict__ whT1,
    const unsigned short* __restrict__ wxT1,
    const float* __restrict__ b0,
    const float* __restrict__ b1,
    float* __restrict__ hlast,
    unsigned* __restrict__ flagbase)
{
    __shared__ unsigned short wlds[32 * 1024];  // 64 KB

    const int lane = threadIdx.x;
    const int bg   = blockIdx.x >> 6;   // 0..3
    const int ct   = blockIdx.x & 63;   // 0..63
    unsigned* flags = flagbase + bg * 128;  // 64 used + 64 pad (line separation)

    run_layer<0>(wlds, xbf, h0, whT0, wxT0, b0, hlast, flags, 0,  lane, bg, ct);
    run_layer<1>(wlds, h0,  h1, whT1, wxT1, b1, hlast, flags, NS, lane, bg, ct);
}

// one block per batch row; mode 1 = relu, 2 = sigmoid
__global__ void dense(const float* __restrict__ in, const float* __restrict__ W,
                      const float* __restrict__ bias, float* __restrict__ out,
                      int K, int N, int mode) {
    int b = blockIdx.x;
    int j = threadIdx.x;
    extern __shared__ float srow[];
    for (int k = j; k < K; k += blockDim.x) srow[k] = in[b * K + k];
    __syncthreads();
    if (j < N) {
        float acc = bias[j];
        for (int k = 0; k < K; ++k) acc += srow[k] * W[k * N + j];
        if (mode == 1) acc = fmaxf(acc, 0.0f);
        else           acc = 1.0f / (1.0f + __expf(-acc));
        out[b * N + j] = acc;
    }
}

extern "C" void kernel_launch(void* const* d_in, const int* in_sizes, int n_in,
                              void* d_out, int out_size, void* d_ws, size_t ws_size,
                              hipStream_t stream) {
    const float* x    = (const float*)d_in[0];
    const float* Wx0  = (const float*)d_in[1];
    const float* Wh0  = (const float*)d_in[2];
    const float* b0   = (const float*)d_in[3];
    const float* Wx1  = (const float*)d_in[4];
    const float* Wh1  = (const float*)d_in[5];
    const float* b1   = (const float*)d_in[6];
    const float* Wd0  = (const float*)d_in[7];
    const float* bd0  = (const float*)d_in[8];
    const float* Wd1  = (const float*)d_in[9];
    const float* bd1  = (const float*)d_in[10];
    const float* Wout = (const float*)d_in[11];
    const float* bout = (const float*)d_in[12];

    char* ws = (char*)d_ws;
    size_t off = 0;
    auto alloc = [&](size_t bytes) { void* p = ws + off; off += (bytes + 255) & ~255ull; return p; };
    unsigned* flagbase = (unsigned*)alloc(4 * 128 * 4);
    unsigned short* xbf  = (unsigned short*)alloc((size_t)NB * NS * NF * 2);
    unsigned short* h0   = (unsigned short*)alloc((size_t)NB * NS * NH * 2);
    unsigned short* h1   = (unsigned short*)alloc((size_t)NB * NS * NH * 2);
    unsigned short* whT0 = (unsigned short*)alloc((size_t)NG * NH * 2);
    unsigned short* wxT0 = (unsigned short*)alloc((size_t)NG * NF * 2);
    unsigned short* whT1 = (unsigned short*)alloc((size_t)NG * NH * 2);
    unsigned short* wxT1 = (unsigned short*)alloc((size_t)NG * NH * 2);
    float* hlast = (float*)alloc((size_t)NB * NH * 4);
    float* dt0   = (float*)alloc((size_t)NB * 512 * 4);
    float* dt1   = (float*)alloc((size_t)NB * 256 * 4);

    hipMemsetAsync(flagbase, 0, 4 * 128 * 4, stream);
    cvt_bf16<<<2048, 256, 0, stream>>>(x, xbf, NB * NS * NF);
    tr_cvt<<<(NG * NF + 255) / 256, 256, 0, stream>>>(Wx0, wxT0, NF, NG);
    tr_cvt<<<(NG * NH + 255) / 256, 256, 0, stream>>>(Wh0, whT0, NH, NG);
    tr_cvt<<<(NG * NH + 255) / 256, 256, 0, stream>>>(Wx1, wxT1, NH, NG);
    tr_cvt<<<(NG * NH + 255) / 256, 256, 0, stream>>>(Wh1, whT1, NH, NG);

    void* args[] = { (void*)&xbf, (void*)&h0, (void*)&h1,
                     (void*)&whT0, (void*)&wxT0, (void*)&whT1, (void*)&wxT1,
                     (void*)&b0, (void*)&b1, (void*)&hlast, (void*)&flagbase };
    hipLaunchCooperativeKernel((void*)lstm_coop, dim3(NBLK), dim3(64), args, 0, stream);

    dense<<<NB, 512, 512 * 4, stream>>>(hlast, Wd0, bd0, dt0, 512, 512, 1);
    dense<<<NB, 256, 512 * 4, stream>>>(dt0, Wd1, bd1, dt1, 512, 256, 1);
    dense<<<NB, 128, 256 * 4, stream>>>(dt1, Wout, bout, (float*)d_out, 256, 96, 2);
}

// Round 4
// 4658.059 us; speedup vs baseline: 7.1809x; 1.4619x over previous
//
#include <hip/hip_runtime.h>

typedef __attribute__((ext_vector_type(8))) short short8;
typedef __attribute__((ext_vector_type(4))) float f32x4;

#define NB 64
#define NS 512
#define NF 128
#define NH 512
#define NG 2048  // 4*H
#define NBLK 256

__device__ __forceinline__ unsigned short f2bf(float f) {
    unsigned int u = __builtin_bit_cast(unsigned int, f);
    u = (u + 0x7fffu + ((u >> 16) & 1u)) >> 16;
    return (unsigned short)u;
}
__device__ __forceinline__ float sigm(float x) { return 1.0f / (1.0f + __expf(-x)); }
__device__ __forceinline__ float tanh_(float x) {
    float e = __expf(2.0f * fabsf(x));
    float r = 1.0f - 2.0f / (e + 1.0f);
    return x < 0.0f ? -r : r;
}

// agent-scope (L2-bypassing, L3-coherent) 16B load as 2x8B
__device__ __forceinline__ short8 cohld16(const unsigned short* p) {
    unsigned long long* q = (unsigned long long*)p;
    union { unsigned long long u[2]; short8 s; } v;
    v.u[0] = __hip_atomic_load(q,     __ATOMIC_RELAXED, __HIP_MEMORY_SCOPE_AGENT);
    v.u[1] = __hip_atomic_load(q + 1, __ATOMIC_RELAXED, __HIP_MEMORY_SCOPE_AGENT);
    return v.s;
}
__device__ __forceinline__ void cohst2(unsigned short* p, unsigned short v) {
    __hip_atomic_store(p, v, __ATOMIC_RELAXED, __HIP_MEMORY_SCOPE_AGENT);
}

__device__ __forceinline__ void flag_wait(const unsigned* flags, int lane, unsigned tgt) {
    while (__hip_atomic_load(&flags[lane], __ATOMIC_RELAXED, __HIP_MEMORY_SCOPE_AGENT) < tgt)
        __builtin_amdgcn_s_sleep(1);
    __builtin_amdgcn_sched_barrier(0);
    asm volatile("" ::: "memory");
}
__device__ __forceinline__ void flag_signal(unsigned* myflag, unsigned val, int lane) {
    asm volatile("s_waitcnt vmcnt(0)" ::: "memory");   // own h-stores at coherence point
    if (lane == 0)
        __hip_atomic_store(myflag, val, __ATOMIC_RELAXED, __HIP_MEMORY_SCOPE_AGENT);
}

__global__ void cvt_bf16(const float* __restrict__ in, unsigned short* __restrict__ out, int n) {
    int i = blockIdx.x * blockDim.x + threadIdx.x;
    int stride = gridDim.x * blockDim.x;
    for (; i < n; i += stride) out[i] = f2bf(in[i]);
}

// out[n][k] = bf16(in[k][n])   in: [K][N] f32 row-major
__global__ void tr_cvt(const float* __restrict__ in, unsigned short* __restrict__ out, int K, int N) {
    int i = blockIdx.x * blockDim.x + threadIdx.x;
    if (i >= K * N) return;
    int n = i / K, k = i - n * K;
    out[i] = f2bf(in[k * N + n]);
}

// Persistent 2-layer LSTM, layer-pipelined: round r computes L0 step r and
// L1 step r-1 in the same block (513 rounds instead of 1024). Staggered flags:
// flagA (h0 ready) signaled mid-round, polled at top of next round — the L1
// half hides its propagation; flagB (h1 ready) symmetric. h0 fragments are
// reused in-register as L1's x-input.
__global__ void __launch_bounds__(64, 1) lstm_coop(
    const unsigned short* __restrict__ xbf,
    unsigned short* __restrict__ h0,
    unsigned short* __restrict__ h1,
    const unsigned short* __restrict__ whT0,
    const unsigned short* __restrict__ wxT0,
    const unsigned short* __restrict__ whT1,
    const unsigned short* __restrict__ wxT1,
    const float* __restrict__ b0,
    const float* __restrict__ b1,
    float* __restrict__ hlast,
    unsigned* __restrict__ flagbase)
{
    __shared__ unsigned short w0lds[32 * 640];    // 40 KB: [32 gate-cols][512+128]
    __shared__ unsigned short w1lds[32 * 1024];   // 64 KB: [32 gate-cols][512+512]

    const int lane = threadIdx.x;
    const int c16  = lane & 15;
    const int kg   = lane >> 4;
    const int bg   = blockIdx.x >> 6;   // 0..3
    const int ct   = blockIdx.x & 63;   // 0..63
    unsigned* flagA = (unsigned*)((char*)flagbase + (size_t)bg * 4096);
    unsigned* flagB = (unsigned*)((char*)flagbase + (size_t)bg * 4096 + 2048);

    // ---- stage both weight slices: local row n -> gate q=n>>3, hcol ct*8+(n&7)
    auto loadw = [&](unsigned short* dst, const unsigned short* whT,
                     const unsigned short* wxT, int Kx, int rowB) {
        int cpr = (NH + Kx) >> 3;
        for (int idx = lane; idx < 32 * cpr; idx += 64) {
            int n = idx / cpr, cc = idx - n * cpr;
            int G = (n >> 3) * NH + ct * 8 + (n & 7);
            uint4 v = (cc < 64) ? *(const uint4*)(whT + (size_t)G * NH + cc * 8)
                                : *(const uint4*)(wxT + (size_t)G * Kx + (size_t)(cc - 64) * 8);
            *(uint4*)((char*)dst + n * rowB + ((cc * 16) ^ ((n & 7) << 4))) = v;
        }
    };
    loadw(w0lds, whT0, wxT0, NF, 1280);
    loadw(w1lds, whT1, wxT1, NH, 2048);
    __syncthreads();

    const int hc8 = c16 & 7;
    const float bi0 = b0[0 * NH + ct * 8 + hc8], bf0 = b0[1 * NH + ct * 8 + hc8];
    const float bg0 = b0[2 * NH + ct * 8 + hc8], bo0 = b0[3 * NH + ct * 8 + hc8];
    const float bi1 = b1[0 * NH + ct * 8 + hc8], bf1 = b1[1 * NH + ct * 8 + hc8];
    const float bg1 = b1[2 * NH + ct * 8 + hc8], bo1 = b1[3 * NH + ct * 8 + hc8];

    const int arow = bg * 16 + c16;
    const size_t aseq = (size_t)arow * NS;
    float cst0[4] = {0.f, 0.f, 0.f, 0.f};
    float cst1[4] = {0.f, 0.f, 0.f, 0.f};

    const char* lA0 = (const char*)w0lds + (size_t)c16 * 1280;
    const char* lB0 = (const char*)w0lds + (size_t)(16 + c16) * 1280;
    const char* lA1 = (const char*)w1lds + (size_t)c16 * 2048;
    const char* lB1 = (const char*)w1lds + (size_t)(16 + c16) * 2048;
    const int swz = (c16 & 7) << 4;   // same for row c16 and 16+c16

    // epilogue: lane l and l^8 hold {i,f} / {g,o} swapped for same hcol
    auto epilogue = [&](f32x4 acc0, f32x4 acc1, float* cst,
                        float bi, float bf_, float bgt, float bo,
                        unsigned short* hseq, int t, bool wlast) {
        f32x4 s0, s1;
        #pragma unroll
        for (int i = 0; i < 4; ++i) {
            s0[i] = __shfl_xor(acc0[i], 8, 64);
            s1[i] = __shfl_xor(acc1[i], 8, 64);
        }
        const bool lower = (c16 < 8);
        unsigned short* hw = hseq + ((size_t)(bg * 16 + kg * 4) * NS + t) * NH + ct * 8 + hc8;
        #pragma unroll
        for (int i = 0; i < 4; ++i) {
            float gi = (lower ? acc0[i] : s0[i]) + bi;
            float gf = (lower ? s0[i] : acc0[i]) + bf_;
            float gg = (lower ? acc1[i] : s1[i]) + bgt;
            float go = (lower ? s1[i] : acc1[i]) + bo;
            float c_ = sigm(gf) * cst[i] + sigm(gi) * tanh_(gg);
            cst[i] = c_;
            float hv = sigm(go) * tanh_(c_);
            if (lower) {
                cohst2(hw + (size_t)i * NS * NH, f2bf(hv));
                if (wlast)
                    hlast[(bg * 16 + kg * 4 + i) * NH + ct * 8 + hc8] = hv;
            }
        }
    };

    short8 hfrag[16];   // h0[r-1] row fragment: reused by L0 h-part AND L1 x-part

    for (int r = 0; r <= NS; ++r) {
        // ---- acquire h0[r-1] (flagA signaled mid-round r-1: usually pre-satisfied)
        if (r > 0) {
            flag_wait(flagA, lane, (unsigned)r);
            const unsigned short* hp = h0 + (aseq + (r - 1)) * NH + kg * 8;
            #pragma unroll
            for (int ks = 0; ks < 16; ++ks) hfrag[ks] = cohld16(hp + ks * 32);
        }
        // ---- L0 half: step r
        if (r < NS) {
            f32x4 a0 = {0.f, 0.f, 0.f, 0.f};
            f32x4 a1 = {0.f, 0.f, 0.f, 0.f};
            const unsigned short* xp = xbf + (aseq + r) * NF + kg * 8;
            #pragma unroll
            for (int ks = 0; ks < 4; ++ks) {          // x-part (K=128, L2-cached)
                short8 a = *(const short8*)(xp + ks * 32);
                int boff = 1024 + ks * 64 + kg * 16;
                a0 = __builtin_amdgcn_mfma_f32_16x16x32_bf16(a, *(const short8*)(lA0 + (boff ^ swz)), a0, 0, 0, 0);
                a1 = __builtin_amdgcn_mfma_f32_16x16x32_bf16(a, *(const short8*)(lB0 + (boff ^ swz)), a1, 0, 0, 0);
            }
            if (r > 0) {
                #pragma unroll
                for (int ks = 0; ks < 16; ++ks) {     // h-part (K=512)
                    int boff = ks * 64 + kg * 16;
                    a0 = __builtin_amdgcn_mfma_f32_16x16x32_bf16(hfrag[ks], *(const short8*)(lA0 + (boff ^ swz)), a0, 0, 0, 0);
                    a1 = __builtin_amdgcn_mfma_f32_16x16x32_bf16(hfrag[ks], *(const short8*)(lB0 + (boff ^ swz)), a1, 0, 0, 0);
                }
            }
            epilogue(a0, a1, cst0, bi0, bf0, bg0, bo0, h0, r, false);
            flag_signal(&flagA[ct], (unsigned)(r + 1), lane);   // h0[r] ready
        }
        // ---- L1 half: step t1 = r-1
        if (r > 0) {
            int t1 = r - 1;
            flag_wait(flagB, lane, (unsigned)t1);   // h1[t1-1] ready (signaled end of round r-1)
            f32x4 a0 = {0.f, 0.f, 0.f, 0.f};
            f32x4 a1 = {0.f, 0.f, 0.f, 0.f};
            #pragma unroll
            for (int ks = 0; ks < 16; ++ks) {         // x-part = h0[t1] (in regs!)
                int boff = 1024 + ks * 64 + kg * 16;
                a0 = __builtin_amdgcn_mfma_f32_16x16x32_bf16(hfrag[ks], *(const short8*)(lA1 + (boff ^ swz)), a0, 0, 0, 0);
                a1 = __builtin_amdgcn_mfma_f32_16x16x32_bf16(hfrag[ks], *(const short8*)(lB1 + (boff ^ swz)), a1, 0, 0, 0);
            }
            if (t1 > 0) {
                const unsigned short* hp = h1 + (aseq + (t1 - 1)) * NH + kg * 8;
                #pragma unroll
                for (int ks = 0; ks < 16; ++ks) {     // h-part (K=512)
                    short8 a = cohld16(hp + ks * 32);
                    int boff = ks * 64 + kg * 16;
                    a0 = __builtin_amdgcn_mfma_f32_16x16x32_bf16(a, *(const short8*)(lA1 + (boff ^ swz)), a0, 0, 0, 0);
                    a1 = __builtin_amdgcn_mfma_f32_16x16x32_bf16(a, *(const short8*)(lB1 + (boff ^ swz)), a1, 0, 0, 0);
                }
            }
            epilogue(a0, a1, cst1, bi1, bf1, bg1, bo1, h1, t1, t1 == NS - 1);
            flag_signal(&flagB[ct], (unsigned)(t1 + 1), lane);  // h1[t1] ready
        }
    }
}

// one block per batch row; mode 1 = relu, 2 = sigmoid
__global__ void dense(const float* __restrict__ in, const float* __restrict__ W,
                      const float* __restrict__ bias, float* __restrict__ out,
                      int K, int N, int mode) {
    int b = blockIdx.x;
    int j = threadIdx.x;
    extern __shared__ float srow[];
    for (int k = j; k < K; k += blockDim.x) srow[k] = in[b * K + k];
    __syncthreads();
    if (j < N) {
        float acc = bias[j];
        for (int k = 0; k < K; ++k) acc += srow[k] * W[k * N + j];
        if (mode == 1) acc = fmaxf(acc, 0.0f);
        else           acc = 1.0f / (1.0f + __expf(-acc));
        out[b * N + j] = acc;
    }
}

extern "C" void kernel_launch(void* const* d_in, const int* in_sizes, int n_in,
                              void* d_out, int out_size, void* d_ws, size_t ws_size,
                              hipStream_t stream) {
    const float* x    = (const float*)d_in[0];
    const float* Wx0  = (const float*)d_in[1];
    const float* Wh0  = (const float*)d_in[2];
    const float* b0   = (const float*)d_in[3];
    const float* Wx1  = (const float*)d_in[4];
    const float* Wh1  = (const float*)d_in[5];
    const float* b1   = (const float*)d_in[6];
    const float* Wd0  = (const float*)d_in[7];
    const float* bd0  = (const float*)d_in[8];
    const float* Wd1  = (const float*)d_in[9];
    const float* bd1  = (const float*)d_in[10];
    const float* Wout = (const float*)d_in[11];
    const float* bout = (const float*)d_in[12];

    char* ws = (char*)d_ws;
    size_t off = 0;
    auto alloc = [&](size_t bytes) { void* p = ws + off; off += (bytes + 255) & ~255ull; return p; };
    unsigned* flagbase = (unsigned*)alloc(4 * 4096);
    unsigned short* xbf  = (unsigned short*)alloc((size_t)NB * NS * NF * 2);
    unsigned short* h0   = (unsigned short*)alloc((size_t)NB * NS * NH * 2);
    unsigned short* h1   = (unsigned short*)alloc((size_t)NB * NS * NH * 2);
    unsigned short* whT0 = (unsigned short*)alloc((size_t)NG * NH * 2);
    unsigned short* wxT0 = (unsigned short*)alloc((size_t)NG * NF * 2);
    unsigned short* whT1 = (unsigned short*)alloc((size_t)NG * NH * 2);
    unsigned short* wxT1 = (unsigned short*)alloc((size_t)NG * NH * 2);
    float* hlast = (float*)alloc((size_t)NB * NH * 4);
    float* dt0   = (float*)alloc((size_t)NB * 512 * 4);
    float* dt1   = (float*)alloc((size_t)NB * 256 * 4);

    hipMemsetAsync(flagbase, 0, 4 * 4096, stream);
    cvt_bf16<<<2048, 256, 0, stream>>>(x, xbf, NB * NS * NF);
    tr_cvt<<<(NG * NF + 255) / 256, 256, 0, stream>>>(Wx0, wxT0, NF, NG);
    tr_cvt<<<(NG * NH + 255) / 256, 256, 0, stream>>>(Wh0, whT0, NH, NG);
    tr_cvt<<<(NG * NH + 255) / 256, 256, 0, stream>>>(Wx1, wxT1, NH, NG);
    tr_cvt<<<(NG * NH + 255) / 256, 256, 0, stream>>>(Wh1, whT1, NH, NG);

    void* args[] = { (void*)&xbf, (void*)&h0, (void*)&h1,
                     (void*)&whT0, (void*)&wxT0, (void*)&whT1, (void*)&wxT1,
                     (void*)&b0, (void*)&b1, (void*)&hlast, (void*)&flagbase };
    hipLaunchCooperativeKernel((void*)lstm_coop, dim3(NBLK), dim3(64), args, 0, stream);

    dense<<<NB, 512, 512 * 4, stream>>>(hlast, Wd0, bd0, dt0, 512, 512, 1);
    dense<<<NB, 256, 512 * 4, stream>>>(dt0, Wd1, bd1, dt1, 512, 256, 1);
    dense<<<NB, 128, 256 * 4, stream>>>(dt1, Wout, bout, (float*)d_out, 256, 96, 2);
}